// Round 5
// baseline (461.664 us; speedup 1.0000x reference)
//
#include <hip/hip_runtime.h>
#include <math.h>

// Problem constants (match reference)
#define NPTS      128
#define NEARV     2.0f
#define FARV      6.0f
#define GRID_RES  128
#define CELLV     0.0234375f   /* 3/128, exact in fp32 */
#define TSZ       256          /* LDS t-table size (max_steps+pad < 256) */

typedef float f4 __attribute__((ext_vector_type(4)));

// ---------------------------------------------------------------------------
// Kernel 1: detect occ_grid storage layout (byte-bools vs int32).
// Reading as u32: byte layout gives words >1 with overwhelming probability at
// 5% occupancy; int32 layout gives only 0/1 words. Scan is in-bounds under
// both layouts (nwords = elem_count/4). flag=1 => byte layout.
// ---------------------------------------------------------------------------
__global__ void detect_layout_kernel(const unsigned int* __restrict__ g,
                                     int nwords, int* __restrict__ flag) {
    int i = blockIdx.x * blockDim.x + threadIdx.x;
    int stride = gridDim.x * blockDim.x;
    int local = 0;
    for (; i < nwords; i += stride)
        if (g[i] > 1u) local = 1;
    if (__any(local) && (threadIdx.x & 63) == 0)
        atomicOr(flag, 1);
}

// ---------------------------------------------------------------------------
// Kernel 2: empty-space-skipping ray march. One thread per ray.
// Bit-exact per-step math vs the reference fori_loop. Latency optimizations
// that provably don't change any decision:
//   (a) fp32 t-chain T[i] precomputed into LDS (ray-independent).
//   (b) conservative slab skip/early-exit. KEY: reference's astype(int32)
//       truncates toward zero, so fractional index in (-1,0) maps to 0 =
//       VALID. The valid region is the box EXPANDED BY ONE CELL on each MIN
//       face. Slab min planes are therefore at -1.5-CELL; with that, the
//       3-step margin only covers fp32 ulps. (Round-2 bug: used -1.5 ->
//       missed reference hits in the phantom cell past the min-face exit.)
//   (c) occ loads batched 4 per group -> 1/4 the latency chain.
// Layout branchless: int32 bools are 0/1 little-endian, so the LSB byte at
// (lin << shift) is the truth value under either layout.
// ---------------------------------------------------------------------------
__global__ __launch_bounds__(256) void march_kernel(
        const float* __restrict__ rays_o,
        const float* __restrict__ dirs,
        const unsigned char* __restrict__ grid,
        const int* __restrict__ flag,
        float* __restrict__ eff_near,
        int n, float step, int max_steps) {
    __shared__ float T[TSZ];
    int tid = threadIdx.x;
    // T[j] = NEAR after j dependent fp32 adds of step (exact reference chain).
    if (tid <= max_steps) {
        float t = NEARV;
        for (int k = 0; k < tid; ++k) t = __fadd_rn(t, step);
        T[tid] = t;
    } else if (tid < TSZ) {
        T[tid] = 1.0e9f;   // pad: triggers 'past' (same FAR outcome) if touched
    }
    __syncthreads();

    int r = blockIdx.x * blockDim.x + tid;
    if (r >= n) return;

    const int shift = (*flag != 0) ? 0 : 2;

    float ox = rays_o[3 * r + 0], oy = rays_o[3 * r + 1], oz = rays_o[3 * r + 2];
    float dx = dirs[3 * r + 0],   dy = dirs[3 * r + 1],   dz = dirs[3 * r + 2];

    // Slab test against the VALID region: [-1.5-CELL, 1.5] per axis
    // (truncation-toward-zero makes frac index (-1,0) -> 0 -> valid).
    const float BMIN = -1.5f - CELLV;
    float t1x = (BMIN - ox) / dx, t2x = (1.5f - ox) / dx;
    float t1y = (BMIN - oy) / dy, t2y = (1.5f - oy) / dy;
    float t1z = (BMIN - oz) / dz, t2z = (1.5f - oz) / dz;
    float tent = fmaxf(fmaxf(fminf(t1x, t2x), fminf(t1y, t2y)),
                       fmaxf(fminf(t1z, t2z), NEARV));
    float texi = fminf(fminf(fmaxf(t1x, t2x), fmaxf(t1y, t2y)),
                       fminf(fmaxf(t1z, t2z), FARV));

    float nn = NEARV;
    if (!(tent <= texi)) {
        // never in the valid region within [near, far] -> first past step = FAR
        nn = FARV;
    } else {
        int i0 = (int)floorf((tent - NEARV) / step) - 3;
        if (i0 < 0) i0 = 0;
        float texm = texi + 3.0f * step;  // valid-region exit + fp-safety margin
        bool done = false;
        for (int i = i0; i < max_steps && !done; i += 4) {
            float tn[4];
            int   lin[4];
            bool  val[4];
#pragma unroll
            for (int j = 0; j < 4; ++j) {
                float t_n = T[i + 1 + j];
                tn[j] = t_n;
                float px = __fadd_rn(ox, __fmul_rn(dx, t_n));
                float py = __fadd_rn(oy, __fmul_rn(dy, t_n));
                float pz = __fadd_rn(oz, __fmul_rn(dz, t_n));
                float fx = __fdiv_rn(__fsub_rn(px, -1.5f), CELLV);
                float fy = __fdiv_rn(__fsub_rn(py, -1.5f), CELLV);
                float fz = __fdiv_rn(__fsub_rn(pz, -1.5f), CELLV);
                int ix = (int)fx;   // trunc toward zero == astype(int32)
                int iy = (int)fy;
                int iz = (int)fz;
                val[j] = ((unsigned)ix < (unsigned)GRID_RES) &
                         ((unsigned)iy < (unsigned)GRID_RES) &
                         ((unsigned)iz < (unsigned)GRID_RES);
                int cx = min(max(ix, 0), GRID_RES - 1);
                int cy = min(max(iy, 0), GRID_RES - 1);
                int cz = min(max(iz, 0), GRID_RES - 1);
                lin[j] = (cx << 14) | (cy << 7) | cz;
            }
            unsigned char oc[4];
#pragma unroll
            for (int j = 0; j < 4; ++j)
                oc[j] = grid[(size_t)((unsigned)lin[j]) << shift];
            for (int j = 0; j < 4 && !done; ++j) {
                bool hit  = val[j] && (oc[j] != 0);
                bool past = tn[j] > FARV;
                if (hit)       { nn = fminf(tn[j], FARV); done = true; }
                else if (past) { nn = FARV;               done = true; }
            }
            if (!done && T[i + 5] > texm) {  // all remaining steps invalid -> FAR
                nn = FARV;
                done = true;
            }
        }
        if (!done) nn = fminf(nn, FARV);  // unreachable in practice; safe default
    }

    eff_near[r] = fminf(nn, FARV);
}

// ---------------------------------------------------------------------------
// Kernel 3: stratified sampling + point generation. One thread per (ray, 4 pts).
// Same per-point fp32 expressions as the passing round-1 version; float4
// loads/stores (16B/lane coalescing) and nontemporal hints on write-once data.
// ---------------------------------------------------------------------------
__device__ __forceinline__ float tval(int i) {
    const float delta = 1.0f / 127.0f;
    return (i >= NPTS - 1) ? 1.0f : __fmul_rn((float)i, delta);
}

__device__ __forceinline__ float zmid(float en, int i) {
    float ti = tval(i);
    return __fadd_rn(__fmul_rn(en, __fsub_rn(1.0f, ti)), __fmul_rn(FARV, ti));
}

__global__ __launch_bounds__(256) void sample_kernel(
        const float* __restrict__ rays_o,
        const float* __restrict__ dirs,
        const float* __restrict__ t_rand,
        const float* __restrict__ eff_near,
        float* __restrict__ out_pts,
        float* __restrict__ out_z,
        int n) {
    int gid = blockIdx.x * blockDim.x + threadIdx.x;
    if (gid >= n * (NPTS / 4)) return;
    int r  = gid >> 5;          // ray index
    int p0 = (gid & 31) << 2;   // first of 4 point indices

    float en = eff_near[r];
    f4 rr = __builtin_nontemporal_load(((const f4*)t_rand) + gid);

    float z[4];
#pragma unroll
    for (int j = 0; j < 4; ++j) {
        int p = p0 + j;
        float zp = zmid(en, p);
        float lower, upper;
        if (p == 0) {
            lower = zp;
        } else {
            lower = __fmul_rn(0.5f, __fadd_rn(zp, zmid(en, p - 1)));
        }
        if (p == NPTS - 1) {
            upper = zp;
        } else {
            upper = __fmul_rn(0.5f, __fadd_rn(zp, zmid(en, p + 1)));
        }
        z[j] = __fadd_rn(lower, __fmul_rn(__fsub_rn(upper, lower), rr[j]));
    }

    f4 zv = { z[0], z[1], z[2], z[3] };
    __builtin_nontemporal_store(zv, ((f4*)out_z) + gid);

    float ox = rays_o[3 * r + 0], oy = rays_o[3 * r + 1], oz = rays_o[3 * r + 2];
    float dx = dirs[3 * r + 0],   dy = dirs[3 * r + 1],   dz = dirs[3 * r + 2];

    float X[4], Y[4], Z[4];
#pragma unroll
    for (int j = 0; j < 4; ++j) {
        X[j] = __fadd_rn(ox, __fmul_rn(dx, z[j]));
        Y[j] = __fadd_rn(oy, __fmul_rn(dy, z[j]));
        Z[j] = __fadd_rn(oz, __fmul_rn(dz, z[j]));
    }

    f4 a = { X[0], Y[0], Z[0], X[1] };
    f4 b = { Y[1], Z[1], X[2], Y[2] };
    f4 c = { Z[2], X[3], Y[3], Z[3] };
    f4* pdst = ((f4*)out_pts) + (size_t)gid * 3;
    __builtin_nontemporal_store(a, pdst + 0);
    __builtin_nontemporal_store(b, pdst + 1);
    __builtin_nontemporal_store(c, pdst + 2);
}

// ---------------------------------------------------------------------------
extern "C" void kernel_launch(void* const* d_in, const int* in_sizes, int n_in,
                              void* d_out, int out_size, void* d_ws, size_t ws_size,
                              hipStream_t stream) {
    const float* rays_o = (const float*)d_in[0];
    const float* dirs   = (const float*)d_in[1];
    const float* t_rand = (const float*)d_in[2];
    const void*  occ    = d_in[3];

    int n    = in_sizes[0] / 3;    // number of rays
    int nocc = in_sizes[3];        // occ grid element count (128^3)

    float* out     = (float*)d_out;
    float* out_pts = out;                               // n*128*3 floats
    float* out_z   = out + (size_t)n * NPTS * 3;        // n*128 floats

    int*   flag = (int*)d_ws;
    float* eff  = (float*)((char*)d_ws + 256);          // n floats

    // STEP exactly as numpy fp32 computes it: 0.5*||cell||, cell=3/128.
    float cell = CELLV;
    float step = 0.5f * sqrtf(3.0f * (cell * cell));
    int max_steps = (int)ceil((6.0 - 2.0) / (double)step) + 2;  // == reference

    hipMemsetAsync(flag, 0, sizeof(int), stream);
    hipLaunchKernelGGL(detect_layout_kernel, dim3(512), dim3(256), 0, stream,
                       (const unsigned int*)occ, nocc / 4, flag);
    hipLaunchKernelGGL(march_kernel, dim3((n + 255) / 256), dim3(256), 0, stream,
                       rays_o, dirs, (const unsigned char*)occ, flag, eff, n, step, max_steps);

    int total4 = n * (NPTS / 4);
    hipLaunchKernelGGL(sample_kernel, dim3((total4 + 255) / 256), dim3(256), 0, stream,
                       rays_o, dirs, t_rand, eff, out_pts, out_z, n);
}

// Round 6
// 417.081 us; speedup vs baseline: 1.1069x; 1.1069x over previous
//
#include <hip/hip_runtime.h>
#include <math.h>

// Problem constants (match reference)
#define NPTS      128
#define NEARV     2.0f
#define FARV      6.0f
#define GRID_RES  128
#define CELLV     0.0234375f   /* 3/128, exact in fp32 */
#define TSZ       256          /* LDS t-table size (max_steps+pad < 256) */
#define RPB       256          /* rays per block (== block size) */

typedef float f4 __attribute__((ext_vector_type(4)));

// ---------------------------------------------------------------------------
// Kernel 1: detect occ_grid storage layout (byte-bools vs int32).
// Reading as u32: byte layout gives words >1 (any of bytes 1..3 set) w.p.
// ~0.143/word at 5% occupancy; int32 layout gives only 0/1 words. Scanning
// 16384 words -> P(no signal | byte layout) ~ 0.857^16384 ~ e^-2500 = 0.
// Scan is in-bounds under both layouts. flag=1 => byte layout.
// ---------------------------------------------------------------------------
__global__ void detect_layout_kernel(const unsigned int* __restrict__ g,
                                     int nwords, int* __restrict__ flag) {
    int i = blockIdx.x * blockDim.x + threadIdx.x;
    int stride = gridDim.x * blockDim.x;
    int local = 0;
    for (; i < nwords; i += stride)
        if (g[i] > 1u) local = 1;
    if (__any(local) && (threadIdx.x & 63) == 0)
        atomicOr(flag, 1);
}

// ---------------------------------------------------------------------------
// Fused kernel: march (1 thread/ray) -> LDS -> stratified sampling (32
// threads/ray, 4 pts/thread-iter). Fusion is exact: sample for ray r depends
// only on eff_near[r], produced by this block's march phase.
//
// March is bit-exact vs the reference fori_loop:
//   (a) fp32 t-chain T[i] (NEAR after i fadds of STEP) precomputed in LDS.
//   (b) conservative slab skip/early-exit. astype(int32) truncates toward
//       zero, so fractional index in (-1,0) maps to 0 = VALID: the valid
//       region is the box EXPANDED BY ONE CELL on each MIN face -> slab min
//       planes at -1.5-CELL; 3-step margins then only cover fp32 ulps.
//   (c) occ loads batched 4 per group -> 1/4 the dependent-latency chain.
// Layout branchless: int32 bools are 0/1 little-endian -> LSB byte at
// (lin << shift) is the truth value under either layout.
// ---------------------------------------------------------------------------
__device__ __forceinline__ float tval(int i) {
    const float delta = 1.0f / 127.0f;
    return (i >= NPTS - 1) ? 1.0f : __fmul_rn((float)i, delta);
}

__device__ __forceinline__ float zmid(float en, int i) {
    float ti = tval(i);
    return __fadd_rn(__fmul_rn(en, __fsub_rn(1.0f, ti)), __fmul_rn(FARV, ti));
}

__global__ __launch_bounds__(RPB) void march_sample_kernel(
        const float* __restrict__ rays_o,
        const float* __restrict__ dirs,
        const float* __restrict__ t_rand,
        const unsigned char* __restrict__ grid,
        const int* __restrict__ flag,
        float* __restrict__ out_pts,
        float* __restrict__ out_z,
        int n, float step, int max_steps) {
    __shared__ float T[TSZ];
    __shared__ float EN[RPB];

    int tid = threadIdx.x;
    // T[j] = NEAR after j dependent fp32 adds of step (exact reference chain).
    if (tid <= max_steps) {
        float t = NEARV;
        for (int k = 0; k < tid; ++k) t = __fadd_rn(t, step);
        T[tid] = t;
    } else if (tid < TSZ) {
        T[tid] = 1.0e9f;   // pad: triggers 'past' (same FAR outcome) if touched
    }
    __syncthreads();

    int rbase = blockIdx.x * RPB;
    int r = rbase + tid;

    // ---------------- march phase (1 thread = 1 ray) ----------------
    float nn = FARV;
    if (r < n) {
        const int shift = (*flag != 0) ? 0 : 2;

        float ox = rays_o[3 * r + 0], oy = rays_o[3 * r + 1], oz = rays_o[3 * r + 2];
        float dx = dirs[3 * r + 0],   dy = dirs[3 * r + 1],   dz = dirs[3 * r + 2];

        // Slab vs the VALID region: [-1.5-CELL, 1.5] per axis.
        const float BMIN = -1.5f - CELLV;
        float t1x = (BMIN - ox) / dx, t2x = (1.5f - ox) / dx;
        float t1y = (BMIN - oy) / dy, t2y = (1.5f - oy) / dy;
        float t1z = (BMIN - oz) / dz, t2z = (1.5f - oz) / dz;
        float tent = fmaxf(fmaxf(fminf(t1x, t2x), fminf(t1y, t2y)),
                           fmaxf(fminf(t1z, t2z), NEARV));
        float texi = fminf(fminf(fmaxf(t1x, t2x), fmaxf(t1y, t2y)),
                           fminf(fmaxf(t1z, t2z), FARV));

        nn = NEARV;
        if (!(tent <= texi)) {
            nn = FARV;   // never in valid region within [near,far]
        } else {
            int i0 = (int)floorf((tent - NEARV) / step) - 3;
            if (i0 < 0) i0 = 0;
            float texm = texi + 3.0f * step;  // exit + fp-safety margin
            bool done = false;
            for (int i = i0; i < max_steps && !done; i += 4) {
                float tn[4];
                int   lin[4];
                bool  val[4];
#pragma unroll
                for (int j = 0; j < 4; ++j) {
                    float t_n = T[i + 1 + j];
                    tn[j] = t_n;
                    float px = __fadd_rn(ox, __fmul_rn(dx, t_n));
                    float py = __fadd_rn(oy, __fmul_rn(dy, t_n));
                    float pz = __fadd_rn(oz, __fmul_rn(dz, t_n));
                    float fx = __fdiv_rn(__fsub_rn(px, -1.5f), CELLV);
                    float fy = __fdiv_rn(__fsub_rn(py, -1.5f), CELLV);
                    float fz = __fdiv_rn(__fsub_rn(pz, -1.5f), CELLV);
                    int ix = (int)fx;   // trunc toward zero == astype(int32)
                    int iy = (int)fy;
                    int iz = (int)fz;
                    val[j] = ((unsigned)ix < (unsigned)GRID_RES) &
                             ((unsigned)iy < (unsigned)GRID_RES) &
                             ((unsigned)iz < (unsigned)GRID_RES);
                    int cx = min(max(ix, 0), GRID_RES - 1);
                    int cy = min(max(iy, 0), GRID_RES - 1);
                    int cz = min(max(iz, 0), GRID_RES - 1);
                    lin[j] = (cx << 14) | (cy << 7) | cz;
                }
                unsigned char oc[4];
#pragma unroll
                for (int j = 0; j < 4; ++j)
                    oc[j] = grid[(size_t)((unsigned)lin[j]) << shift];
                for (int j = 0; j < 4 && !done; ++j) {
                    bool hit  = val[j] && (oc[j] != 0);
                    bool past = tn[j] > FARV;
                    if (hit)       { nn = fminf(tn[j], FARV); done = true; }
                    else if (past) { nn = FARV;               done = true; }
                }
                if (!done && T[i + 5] > texm) {  // remaining steps all invalid
                    nn = FARV;
                    done = true;
                }
            }
            if (!done) nn = fminf(nn, FARV);
        }
        nn = fminf(nn, FARV);
    }
    EN[tid] = nn;
    __syncthreads();

    // ---------------- sample phase (32 threads/ray, 4 pts each) ----------------
    // group g in [0, RPB*32): local ray rl = g>>5, point block p0 = (g&31)*4.
    for (int k = 0; k < RPB / 8; ++k) {
        int g  = k * RPB + tid;
        int rl = g >> 5;
        int gr = rbase + rl;
        if (gr >= n) break;
        int p0 = (g & 31) << 2;
        int gid = (rbase << 5) + g;      // == gr*32 + (g&31): global f4 index

        float en = EN[rl];
        f4 rr = __builtin_nontemporal_load(((const f4*)t_rand) + gid);

        float z[4];
#pragma unroll
        for (int j = 0; j < 4; ++j) {
            int p = p0 + j;
            float zp = zmid(en, p);
            float lower, upper;
            if (p == 0) {
                lower = zp;
            } else {
                lower = __fmul_rn(0.5f, __fadd_rn(zp, zmid(en, p - 1)));
            }
            if (p == NPTS - 1) {
                upper = zp;
            } else {
                upper = __fmul_rn(0.5f, __fadd_rn(zp, zmid(en, p + 1)));
            }
            z[j] = __fadd_rn(lower, __fmul_rn(__fsub_rn(upper, lower), rr[j]));
        }

        f4 zv = { z[0], z[1], z[2], z[3] };
        __builtin_nontemporal_store(zv, ((f4*)out_z) + gid);

        float ox = rays_o[3 * gr + 0], oy = rays_o[3 * gr + 1], oz = rays_o[3 * gr + 2];
        float dx = dirs[3 * gr + 0],   dy = dirs[3 * gr + 1],   dz = dirs[3 * gr + 2];

        float X[4], Y[4], Z[4];
#pragma unroll
        for (int j = 0; j < 4; ++j) {
            X[j] = __fadd_rn(ox, __fmul_rn(dx, z[j]));
            Y[j] = __fadd_rn(oy, __fmul_rn(dy, z[j]));
            Z[j] = __fadd_rn(oz, __fmul_rn(dz, z[j]));
        }

        f4 a = { X[0], Y[0], Z[0], X[1] };
        f4 b = { Y[1], Z[1], X[2], Y[2] };
        f4 c = { Z[2], X[3], Y[3], Z[3] };
        f4* pdst = ((f4*)out_pts) + (size_t)gid * 3;
        __builtin_nontemporal_store(a, pdst + 0);
        __builtin_nontemporal_store(b, pdst + 1);
        __builtin_nontemporal_store(c, pdst + 2);
    }
}

// ---------------------------------------------------------------------------
extern "C" void kernel_launch(void* const* d_in, const int* in_sizes, int n_in,
                              void* d_out, int out_size, void* d_ws, size_t ws_size,
                              hipStream_t stream) {
    const float* rays_o = (const float*)d_in[0];
    const float* dirs   = (const float*)d_in[1];
    const float* t_rand = (const float*)d_in[2];
    const void*  occ    = d_in[3];

    int n    = in_sizes[0] / 3;    // number of rays
    int nocc = in_sizes[3];        // occ grid element count (128^3)

    float* out     = (float*)d_out;
    float* out_pts = out;                               // n*128*3 floats
    float* out_z   = out + (size_t)n * NPTS * 3;        // n*128 floats

    int* flag = (int*)d_ws;

    // STEP exactly as numpy fp32 computes it: 0.5*||cell||, cell=3/128.
    float cell = CELLV;
    float step = 0.5f * sqrtf(3.0f * (cell * cell));
    int max_steps = (int)ceil((6.0 - 2.0) / (double)step) + 2;  // == reference

    hipMemsetAsync(flag, 0, sizeof(int), stream);

    int scan_words = nocc / 4;
    if (scan_words > 16384) scan_words = 16384;
    hipLaunchKernelGGL(detect_layout_kernel, dim3(16), dim3(256), 0, stream,
                       (const unsigned int*)occ, scan_words, flag);

    hipLaunchKernelGGL(march_sample_kernel, dim3((n + RPB - 1) / RPB), dim3(RPB), 0, stream,
                       rays_o, dirs, t_rand, (const unsigned char*)occ, flag,
                       out_pts, out_z, n, step, max_steps);
}

// Round 7
// 416.423 us; speedup vs baseline: 1.1086x; 1.0016x over previous
//
#include <hip/hip_runtime.h>
#include <math.h>

// Problem constants (match reference)
#define NPTS      128
#define NEARV     2.0f
#define FARV      6.0f
#define GRID_RES  128
#define CELLV     0.0234375f   /* 3/128, exact in fp32 */
#define TSZ       256          /* LDS t-table size (max_steps+pad < 256) */
#define BLOCK     256          /* threads per block */
#define RPB       64           /* rays per block: 2048 blocks -> 8 waves/SIMD */

typedef float f4 __attribute__((ext_vector_type(4)));

// ---------------------------------------------------------------------------
// Kernel 1: detect occ_grid storage layout (byte-bools vs int32).
// Reading as u32: byte layout gives words >1 (any of bytes 1..3 set) w.p.
// ~0.143/word at 5% occupancy; int32 layout gives only 0/1 words. Scanning
// 16384 words -> P(no signal | byte layout) ~ 0.857^16384 ~ 0.
// Scan is in-bounds under both layouts. flag=1 => byte layout.
// ---------------------------------------------------------------------------
__global__ void detect_layout_kernel(const unsigned int* __restrict__ g,
                                     int nwords, int* __restrict__ flag) {
    int i = blockIdx.x * blockDim.x + threadIdx.x;
    int stride = gridDim.x * blockDim.x;
    int local = 0;
    for (; i < nwords; i += stride)
        if (g[i] > 1u) local = 1;
    if (__any(local) && (threadIdx.x & 63) == 0)
        atomicOr(flag, 1);
}

// ---------------------------------------------------------------------------
// Fused kernel: march (threads 0..RPB-1, 1 thread/ray) -> LDS -> stratified
// sampling (all BLOCK threads, 4 pts per thread-iteration, 8 iterations).
// Fusion exact: sample for ray r depends only on eff_near[r] from this block.
//
// March is bit-exact vs the reference fori_loop:
//   (a) fp32 t-chain T[i] (NEAR after i fadds of STEP) precomputed in LDS.
//   (b) conservative slab skip/early-exit. astype(int32) truncates toward
//       zero, so fractional index in (-1,0) maps to 0 = VALID: the valid
//       region is the box EXPANDED BY ONE CELL on each MIN face -> slab min
//       planes at -1.5-CELL; 3-step margins then only cover fp32 ulps.
//   (c) occ loads batched 4 per group -> 1/4 the dependent-latency chain.
// Layout branchless: int32 bools are 0/1 little-endian -> LSB byte at
// (lin << shift) is the truth value under either layout.
// ---------------------------------------------------------------------------
__device__ __forceinline__ float tval(int i) {
    const float delta = 1.0f / 127.0f;
    return (i >= NPTS - 1) ? 1.0f : __fmul_rn((float)i, delta);
}

__device__ __forceinline__ float zmid(float en, int i) {
    float ti = tval(i);
    return __fadd_rn(__fmul_rn(en, __fsub_rn(1.0f, ti)), __fmul_rn(FARV, ti));
}

__global__ __launch_bounds__(BLOCK) void march_sample_kernel(
        const float* __restrict__ rays_o,
        const float* __restrict__ dirs,
        const float* __restrict__ t_rand,
        const unsigned char* __restrict__ grid,
        const int* __restrict__ flag,
        float* __restrict__ out_pts,
        float* __restrict__ out_z,
        int n, float step, int max_steps) {
    __shared__ float T[TSZ];
    __shared__ float EN[RPB];

    int tid = threadIdx.x;
    // T[j] = NEAR after j dependent fp32 adds of step (exact reference chain).
    if (tid <= max_steps) {
        float t = NEARV;
        for (int k = 0; k < tid; ++k) t = __fadd_rn(t, step);
        T[tid] = t;
    } else if (tid < TSZ) {
        T[tid] = 1.0e9f;   // pad: triggers 'past' (same FAR outcome) if touched
    }
    __syncthreads();

    int rbase = blockIdx.x * RPB;

    // ---------------- march phase (threads 0..RPB-1, 1 thread = 1 ray) -----
    if (tid < RPB) {
        int r = rbase + tid;
        float nn = FARV;
        if (r < n) {
            const int shift = (*flag != 0) ? 0 : 2;

            float ox = rays_o[3 * r + 0], oy = rays_o[3 * r + 1], oz = rays_o[3 * r + 2];
            float dx = dirs[3 * r + 0],   dy = dirs[3 * r + 1],   dz = dirs[3 * r + 2];

            // Slab vs the VALID region: [-1.5-CELL, 1.5] per axis.
            const float BMIN = -1.5f - CELLV;
            float t1x = (BMIN - ox) / dx, t2x = (1.5f - ox) / dx;
            float t1y = (BMIN - oy) / dy, t2y = (1.5f - oy) / dy;
            float t1z = (BMIN - oz) / dz, t2z = (1.5f - oz) / dz;
            float tent = fmaxf(fmaxf(fminf(t1x, t2x), fminf(t1y, t2y)),
                               fmaxf(fminf(t1z, t2z), NEARV));
            float texi = fminf(fminf(fmaxf(t1x, t2x), fmaxf(t1y, t2y)),
                               fminf(fmaxf(t1z, t2z), FARV));

            nn = NEARV;
            if (!(tent <= texi)) {
                nn = FARV;   // never in valid region within [near,far]
            } else {
                int i0 = (int)floorf((tent - NEARV) / step) - 3;
                if (i0 < 0) i0 = 0;
                float texm = texi + 3.0f * step;  // exit + fp-safety margin
                bool done = false;
                for (int i = i0; i < max_steps && !done; i += 4) {
                    float tn[4];
                    int   lin[4];
                    bool  val[4];
#pragma unroll
                    for (int j = 0; j < 4; ++j) {
                        float t_n = T[i + 1 + j];
                        tn[j] = t_n;
                        float px = __fadd_rn(ox, __fmul_rn(dx, t_n));
                        float py = __fadd_rn(oy, __fmul_rn(dy, t_n));
                        float pz = __fadd_rn(oz, __fmul_rn(dz, t_n));
                        float fx = __fdiv_rn(__fsub_rn(px, -1.5f), CELLV);
                        float fy = __fdiv_rn(__fsub_rn(py, -1.5f), CELLV);
                        float fz = __fdiv_rn(__fsub_rn(pz, -1.5f), CELLV);
                        int ix = (int)fx;   // trunc toward zero == astype(int32)
                        int iy = (int)fy;
                        int iz = (int)fz;
                        val[j] = ((unsigned)ix < (unsigned)GRID_RES) &
                                 ((unsigned)iy < (unsigned)GRID_RES) &
                                 ((unsigned)iz < (unsigned)GRID_RES);
                        int cx = min(max(ix, 0), GRID_RES - 1);
                        int cy = min(max(iy, 0), GRID_RES - 1);
                        int cz = min(max(iz, 0), GRID_RES - 1);
                        lin[j] = (cx << 14) | (cy << 7) | cz;
                    }
                    unsigned char oc[4];
#pragma unroll
                    for (int j = 0; j < 4; ++j)
                        oc[j] = grid[(size_t)((unsigned)lin[j]) << shift];
                    for (int j = 0; j < 4 && !done; ++j) {
                        bool hit  = val[j] && (oc[j] != 0);
                        bool past = tn[j] > FARV;
                        if (hit)       { nn = fminf(tn[j], FARV); done = true; }
                        else if (past) { nn = FARV;               done = true; }
                    }
                    if (!done && T[i + 5] > texm) {  // remaining steps all invalid
                        nn = FARV;
                        done = true;
                    }
                }
                if (!done) nn = fminf(nn, FARV);
            }
            nn = fminf(nn, FARV);
        }
        EN[tid] = nn;
    }
    __syncthreads();

    // ------------- sample phase (32 threads/ray, 4 pts each) ---------------
    // f4 groups per block: RPB*32 = 2048; per thread: 2048/BLOCK = 8 iters.
    for (int k = 0; k < (RPB * 32) / BLOCK; ++k) {
        int g  = k * BLOCK + tid;
        int rl = g >> 5;
        int gr = rbase + rl;
        if (gr >= n) break;
        int gid = (rbase << 5) + g;      // == gr*32 + (g&31): global f4 index
        int p0 = (g & 31) << 2;

        float en = EN[rl];
        f4 rr = __builtin_nontemporal_load(((const f4*)t_rand) + gid);

        float z[4];
#pragma unroll
        for (int j = 0; j < 4; ++j) {
            int p = p0 + j;
            float zp = zmid(en, p);
            float lower, upper;
            if (p == 0) {
                lower = zp;
            } else {
                lower = __fmul_rn(0.5f, __fadd_rn(zp, zmid(en, p - 1)));
            }
            if (p == NPTS - 1) {
                upper = zp;
            } else {
                upper = __fmul_rn(0.5f, __fadd_rn(zp, zmid(en, p + 1)));
            }
            z[j] = __fadd_rn(lower, __fmul_rn(__fsub_rn(upper, lower), rr[j]));
        }

        f4 zv = { z[0], z[1], z[2], z[3] };
        __builtin_nontemporal_store(zv, ((f4*)out_z) + gid);

        float ox = rays_o[3 * gr + 0], oy = rays_o[3 * gr + 1], oz = rays_o[3 * gr + 2];
        float dx = dirs[3 * gr + 0],   dy = dirs[3 * gr + 1],   dz = dirs[3 * gr + 2];

        float X[4], Y[4], Z[4];
#pragma unroll
        for (int j = 0; j < 4; ++j) {
            X[j] = __fadd_rn(ox, __fmul_rn(dx, z[j]));
            Y[j] = __fadd_rn(oy, __fmul_rn(dy, z[j]));
            Z[j] = __fadd_rn(oz, __fmul_rn(dz, z[j]));
        }

        f4 a = { X[0], Y[0], Z[0], X[1] };
        f4 b = { Y[1], Z[1], X[2], Y[2] };
        f4 c = { Z[2], X[3], Y[3], Z[3] };
        f4* pdst = ((f4*)out_pts) + (size_t)gid * 3;
        __builtin_nontemporal_store(a, pdst + 0);
        __builtin_nontemporal_store(b, pdst + 1);
        __builtin_nontemporal_store(c, pdst + 2);
    }
}

// ---------------------------------------------------------------------------
extern "C" void kernel_launch(void* const* d_in, const int* in_sizes, int n_in,
                              void* d_out, int out_size, void* d_ws, size_t ws_size,
                              hipStream_t stream) {
    const float* rays_o = (const float*)d_in[0];
    const float* dirs   = (const float*)d_in[1];
    const float* t_rand = (const float*)d_in[2];
    const void*  occ    = d_in[3];

    int n    = in_sizes[0] / 3;    // number of rays
    int nocc = in_sizes[3];        // occ grid element count (128^3)

    float* out     = (float*)d_out;
    float* out_pts = out;                               // n*128*3 floats
    float* out_z   = out + (size_t)n * NPTS * 3;        // n*128 floats

    int* flag = (int*)d_ws;

    // STEP exactly as numpy fp32 computes it: 0.5*||cell||, cell=3/128.
    float cell = CELLV;
    float step = 0.5f * sqrtf(3.0f * (cell * cell));
    int max_steps = (int)ceil((6.0 - 2.0) / (double)step) + 2;  // == reference

    hipMemsetAsync(flag, 0, sizeof(int), stream);

    int scan_words = nocc / 4;
    if (scan_words > 16384) scan_words = 16384;
    hipLaunchKernelGGL(detect_layout_kernel, dim3(16), dim3(256), 0, stream,
                       (const unsigned int*)occ, scan_words, flag);

    hipLaunchKernelGGL(march_sample_kernel, dim3((n + RPB - 1) / RPB), dim3(BLOCK), 0, stream,
                       rays_o, dirs, t_rand, (const unsigned char*)occ, flag,
                       out_pts, out_z, n, step, max_steps);
}